// Round 8
// baseline (563.856 us; speedup 1.0000x reference)
//
#include <hip/hip_runtime.h>

// Problem constants
#define N_NODES 100000
#define N_EDGES 1600000
#define HDIM    64
#define NGRAPH  64
#define BW      256                      // bucket width (nodes); shift = 8
#define NB      391                      // ceil(N_NODES / BW)
#define PADS    772                      // per-bucket rec slack (align + pad4)
#define EPAD    (N_EDGES + NB * PADS + 16) // rec capacity (int records)
#define NBLK    256                      // edge-pass blocks
#define CHUNK   ((N_EDGES + NBLK - 1) / NBLK)
#define MTILES  (N_NODES / 16)           // 6250 GEMM m-tiles

// native fp16, no hip_fp16 header
typedef _Float16 h16;
typedef _Float16 h16x4 __attribute__((ext_vector_type(4)));
typedef _Float16 h16x8 __attribute__((ext_vector_type(8)));
typedef float    f32x4 __attribute__((ext_vector_type(4)));

// ----------------------------------------- K1: per-(block,bucket) edge counts
__global__ __launch_bounds__(512) void bucket_count(const int* __restrict__ ei,
                                                    int* __restrict__ cntTabA,
                                                    int* __restrict__ cntTabT) {
    __shared__ int cA[NB], cT[NB];
    const int tid = threadIdx.x;
    for (int i = tid; i < NB; i += 512) { cA[i] = 0; cT[i] = 0; }
    __syncthreads();
    const int e0 = blockIdx.x * CHUNK, e1 = min(e0 + CHUNK, N_EDGES);
    for (int e = e0 + tid; e < e1; e += 512) {
        int r = ei[e];
        int c = ei[N_EDGES + e];
        atomicAdd(&cA[r >> 8], 1);
        atomicAdd(&cT[c >> 8], 1);
    }
    __syncthreads();
    for (int b = tid; b < NB; b += 512) {
        cntTabA[b * NBLK + blockIdx.x] = cA[b];
        cntTabT[b * NBLK + blockIdx.x] = cT[b];
    }
}

// ---------------- K2a: per-bucket LDS scan of the 256 per-block counts
__global__ __launch_bounds__(256) void chunk_scan(int* __restrict__ cntTabA,
                                                  int* __restrict__ cntTabT,
                                                  int* __restrict__ tot) {
    __shared__ int s[256];
    const int b = blockIdx.x, d = blockIdx.y, tid = threadIdx.x;
    int* tab = d ? cntTabT : cntTabA;
    int v = tab[b * NBLK + tid];
    s[tid] = v;
    __syncthreads();
    for (int off = 1; off < 256; off <<= 1) {
        int t = (tid >= off) ? s[tid - off] : 0;
        __syncthreads();
        s[tid] += t;
        __syncthreads();
    }
    tab[b * NBLK + tid] = s[tid] - v;       // exclusive within bucket
    if (tid == 255) tot[d * 512 + b] = s[255];
}

// ---------------- K2b: bucket-start scan (both dirs, one block, parallel)
__global__ __launch_bounds__(512) void start_scan(const int* __restrict__ tot,
                                                  int* __restrict__ bktStartA,
                                                  int* __restrict__ bktStartT) {
    __shared__ int s[512];
    const int tid = threadIdx.x;
    int v = (tid < NB) ? tot[tid] : 0;
    s[tid] = v;
    __syncthreads();
    for (int off = 1; off < 512; off <<= 1) {
        int t = (tid >= off) ? s[tid - off] : 0;
        __syncthreads();
        s[tid] += t;
        __syncthreads();
    }
    if (tid < NB) bktStartA[tid] = s[tid] - v;
    if (tid == 0) bktStartA[NB] = N_EDGES;
    __syncthreads();
    int v2 = (tid < NB) ? tot[512 + tid] : 0;
    s[tid] = v2;
    __syncthreads();
    for (int off = 1; off < 512; off <<= 1) {
        int t = (tid >= off) ? s[tid - off] : 0;
        __syncthreads();
        s[tid] += t;
        __syncthreads();
    }
    if (tid < NB) bktStartT[tid] = s[tid] - v2;
    if (tid == 0) bktStartT[NB] = N_EDGES;
}

// --------------------------- K3: bucketize write (bases pre-reserved)
// packed 4B entries: (src << 8) | (tgt & 255)
__global__ __launch_bounds__(512) void bucketize_write(const int* __restrict__ ei,
                                                       const int* __restrict__ cntTabA,
                                                       const int* __restrict__ cntTabT,
                                                       const int* __restrict__ bktStartA,
                                                       const int* __restrict__ bktStartT,
                                                       int* __restrict__ bktA,
                                                       int* __restrict__ bktT) {
    __shared__ int bA[NB], bT[NB];
    const int tid = threadIdx.x;
    for (int i = tid; i < NB; i += 512) {
        bA[i] = bktStartA[i] + cntTabA[i * NBLK + blockIdx.x];
        bT[i] = bktStartT[i] + cntTabT[i * NBLK + blockIdx.x];
    }
    __syncthreads();
    const int e0 = blockIdx.x * CHUNK, e1 = min(e0 + CHUNK, N_EDGES);
    for (int e = e0 + tid; e < e1; e += 512) {
        int r = ei[e];
        int c = ei[N_EDGES + e];
        int pA = atomicAdd(&bA[r >> 8], 1);
        bktA[pA] = (c << 8) | (r & 255);     // tgt=r, src=c
        int pT = atomicAdd(&bT[c >> 8], 1);
        bktT[pT] = (r << 8) | (c & 255);     // tgt=c, src=r
    }
}

// ----- K4 (merged): degrees + rsqrt + padded ptrs + counting scatter.
// One kernel per (bucket, dir): count -> scan -> scatter; the second edge
// pass hits L2 (bucket ~16KB). rec base for bucket b = align4(bktStart[b])
// + b*PADS, so regions are int4-aligned and never overlap (pad4 <= 3/node).
// Records are 4B raw src indices (weights factored out; see agg).
__global__ __launch_bounds__(256) void bucket_deg_scatter(
        const int* __restrict__ bktStartA, const int* __restrict__ bktStartT,
        const int* __restrict__ bktA, const int* __restrict__ bktT,
        int* __restrict__ deg_out, int* __restrict__ deg_in,
        float* __restrict__ r_out, float* __restrict__ r_in,
        int* __restrict__ rowptrP, int* __restrict__ colptrP,
        int* __restrict__ recA, int* __restrict__ recT) {
    __shared__ int c[BW];
    __shared__ int sc[256];
    const int b = blockIdx.x, d = blockIdx.y, tid = threadIdx.x;
    const int* bs = d ? bktStartT : bktStartA;
    const int* bkt = d ? bktT : bktA;
    int* deg = d ? deg_in : deg_out;
    float* rr = d ? r_in : r_out;
    int* ptr = d ? colptrP : rowptrP;
    int* rec = d ? recT : recA;
    const int node0 = b * BW;
    c[tid] = 0;
    __syncthreads();
    const int i0 = bs[b], i1 = bs[b + 1];
    for (int i = i0 + tid; i < i1; i += 256) atomicAdd(&c[bkt[i] & 255], 1);
    __syncthreads();
    const int n = node0 + tid;
    int dg = c[tid];
    int pad = (n < N_NODES) ? ((dg + 3) & ~3) : 0;
    if (n < N_NODES) {
        deg[n] = dg;
        rr[n] = dg > 0 ? rsqrtf((float)dg) : 0.0f;
    }
    sc[tid] = pad;
    __syncthreads();
    for (int off = 1; off < 256; off <<= 1) {
        int t = (tid >= off) ? sc[tid - off] : 0;
        __syncthreads();
        sc[tid] += t;
        __syncthreads();
    }
    const int recBase = ((i0 + 3) & ~3) + b * PADS;
    int myStart = recBase + (sc[tid] - pad);
    if (n < N_NODES) ptr[n] = myStart;
    c[tid] = myStart;                        // cur cursor
    __syncthreads();
    for (int i = i0 + tid; i < i1; i += 256) {
        int e = bkt[i];
        int p = atomicAdd(&c[e & 255], 1);
        rec[p] = e >> 8;                     // raw src index
    }
}

// ---------------------------------------- x -> fp16 cast (+ zero pooled g)
__global__ __launch_bounds__(256) void cast_kernel(const float4* __restrict__ x,
                                                   h16x4* __restrict__ xh,
                                                   unsigned* __restrict__ g) {
    if (blockIdx.x == 0) {
        for (int j = threadIdx.x; j < NGRAPH * HDIM; j += 256) g[j] = 0u;
    }
    int i = blockIdx.x * 256 + threadIdx.x;   // over N*64/4 float4s
    if (i < N_NODES * 16) {
        float4 v = x[i];
        h16x4 o;
        o.x = (h16)v.x; o.y = (h16)v.y; o.z = (h16)v.z; o.w = (h16)v.w;
        xh[i] = o;
    }
}

// ------------------------- weight prep: WT[l][f][k] = 0.5*Wcat^T fp16, bcat
__global__ __launch_bounds__(256) void wprep_kernel(
        const float* __restrict__ w1s, const float* __restrict__ w1d,
        const float* __restrict__ w2s, const float* __restrict__ w2d,
        const float* __restrict__ w3s, const float* __restrict__ w3d,
        const float* __restrict__ b1s, const float* __restrict__ b1d,
        const float* __restrict__ b2s, const float* __restrict__ b2d,
        const float* __restrict__ b3s, const float* __restrict__ b3d,
        h16* __restrict__ WT, float* __restrict__ bc) {
    const int l = blockIdx.y;
    const float* ws = l == 0 ? w1s : l == 1 ? w2s : w3s;
    const float* wd = l == 0 ? w1d : l == 1 ? w2d : w3d;
    int e = blockIdx.x * 256 + threadIdx.x;
    if (e < 8192) {
        int f = e >> 7, k = e & 127;
        float v = (k < 64) ? ws[k * 64 + f] : wd[(k - 64) * 64 + f];
        WT[l * 8192 + f * 128 + k] = (h16)(0.5f * v);
    }
    if (blockIdx.x == 0 && threadIdx.x < 64) {
        const float* bs = l == 0 ? b1s : l == 1 ? b2s : b3s;
        const float* bd = l == 0 ? b1d : l == 1 ? b2d : b3d;
        bc[l * 64 + threadIdx.x] = 0.5f * (bs[threadIdx.x] + bd[threadIdx.x]);
    }
}

// ------------------------------------------------ aggregation (LDS-free)
__device__ __forceinline__ void fma4h(float4& a, float w, h16x4 f) {
    a.x = fmaf(w, (float)f.x, a.x);
    a.y = fmaf(w, (float)f.y, a.y);
    a.z = fmaf(w, (float)f.z, a.z);
    a.w = fmaf(w, (float)f.w, a.w);
}

__device__ __forceinline__ float4 red_s(float4 v) {
    v.x += __shfl_xor(v.x, 16); v.y += __shfl_xor(v.y, 16);
    v.z += __shfl_xor(v.z, 16); v.w += __shfl_xor(v.w, 16);
    v.x += __shfl_xor(v.x, 32); v.y += __shfl_xor(v.y, 32);
    v.z += __shfl_xor(v.z, 32); v.w += __shfl_xor(v.w, 32);
    return v;
}

__device__ __forceinline__ h16x4 ld_h4(const char* __restrict__ p) {
    return *(const h16x4*)p;
}

// per-wave aggregation; lane (q,s): q = feature quad, s = edge-quad slot.
// records = raw src; per-edge weight = rs[src] (400KB L2-resident broadcast
// load); target-side factor applied after reduction. sh2 = log2(row bytes).
__device__ __forceinline__ float4 agg_dir(const char* __restrict__ hb,
                                          const int* __restrict__ rec,
                                          const float* __restrict__ rs,
                                          int start, int deg, int q, int s, int sh2) {
    float4 a0 = {0.f,0.f,0.f,0.f}, a1 = {0.f,0.f,0.f,0.f};
    float4 a2 = {0.f,0.f,0.f,0.f}, a3 = {0.f,0.f,0.f,0.f};
    const int4* rec4 = (const int4*)(rec + start);
    const int qb = q * 8;
    int k = 0;
    for (; k + 16 <= deg; k += 16) {
        int4 p = rec4[(k >> 2) + s];
        float w0 = rs[p.x], w1 = rs[p.y], w2 = rs[p.z], w3 = rs[p.w];
        h16x4 f0 = ld_h4(hb + (p.x << sh2) + qb);
        h16x4 f1 = ld_h4(hb + (p.y << sh2) + qb);
        h16x4 f2 = ld_h4(hb + (p.z << sh2) + qb);
        h16x4 f3 = ld_h4(hb + (p.w << sh2) + qb);
        fma4h(a0, w0, f0);
        fma4h(a1, w1, f1);
        fma4h(a2, w2, f2);
        fma4h(a3, w3, f3);
    }
    int rem = deg - k;
    if (rem > 0) {
        int4 p = rec4[(k >> 2) + s];         // in-bounds via EPAD tail guard
        int base = 4 * s;
        if (base < rem)
            fma4h(a0, rs[p.x], ld_h4(hb + (p.x << sh2) + qb));
        if (base + 1 < rem)
            fma4h(a1, rs[p.y], ld_h4(hb + (p.y << sh2) + qb));
        if (base + 2 < rem)
            fma4h(a2, rs[p.z], ld_h4(hb + (p.z << sh2) + qb));
        if (base + 3 < rem)
            fma4h(a3, rs[p.w], ld_h4(hb + (p.w << sh2) + qb));
    }
    a0.x += a1.x; a0.y += a1.y; a0.z += a1.z; a0.w += a1.w;
    a2.x += a3.x; a2.y += a3.y; a2.z += a3.z; a2.w += a3.w;
    a0.x += a2.x; a0.y += a2.y; a0.z += a2.z; a0.w += a2.w;
    return red_s(a0);
}

// no LDS, no barrier: one wave per (node, dir); dirs write disjoint halves.
__global__ __launch_bounds__(256) void agg_kernel(
        const char* __restrict__ h_in, char* __restrict__ acc_out, int sh2,
        const int* __restrict__ rowptrP, const int* __restrict__ deg_out,
        const int* __restrict__ recA,
        const int* __restrict__ colptrP, const int* __restrict__ deg_in,
        const int* __restrict__ recT,
        const float* __restrict__ r_out, const float* __restrict__ r_in) {
    const int tid  = threadIdx.x;
    const int wid  = (blockIdx.x << 2) + (tid >> 6);   // global wave id
    const int lane = tid & 63;
    const int node = wid >> 1;
    const int dir  = wid & 1;
    const int q = lane & 15;
    const int s = lane >> 4;

    const int* ptr = dir ? colptrP : rowptrP;
    const int* deg = dir ? deg_in : deg_out;
    const int* rec = dir ? recT : recA;
    const float* rs = dir ? r_out : r_in;    // src-side factor
    const float* rt = dir ? r_in : r_out;    // tgt-side factor

    float4 a = agg_dir(h_in, rec, rs, ptr[node], deg[node], q, s, sh2);
    if (s == 0) {
        float w = rt[node];
        h16x4 pk;
        pk.x = (h16)(a.x * w); pk.y = (h16)(a.y * w);
        pk.z = (h16)(a.z * w); pk.w = (h16)(a.w * w);
        *(h16x4*)(acc_out + (size_t)node * 256 + dir * 128 + q * 8) = pk;
    }
}

// --------------------------------------- GEMM via MFMA, h written in place
// acc rows are 256B ([128] fp16); h = ReLU(acc @ WT^T + bc) written into the
// first 128B of each row. Optional fused max-pool (layer 3): batch is sorted,
// so most 16-node tiles map to one graph -> shfl-reduce + 1 atomic per feat.
__global__ __launch_bounds__(256) void gemm_kernel(char* __restrict__ acc,
                                                   const h16* __restrict__ WT,
                                                   const float* __restrict__ bc,
                                                   const int* __restrict__ batch,
                                                   unsigned* __restrict__ g,
                                                   int do_pool) {
    const int lane = threadIdx.x & 63;
    const int wid = (blockIdx.x * 256 + threadIdx.x) >> 6;
    const int nW = gridDim.x * 4;
    const int m = lane & 15, t = lane >> 4;

    h16x8 bfrag[4][4];
    float bb[4];
#pragma unroll
    for (int nt = 0; nt < 4; nt++) {
        bb[nt] = bc[nt * 16 + m];
#pragma unroll
        for (int kk = 0; kk < 4; kk++)
            bfrag[nt][kk] = *(const h16x8*)(WT + (nt * 16 + m) * 128 + kk * 32 + t * 8);
    }

    for (int tile = wid; tile < MTILES; tile += nW) {
        char* arow = acc + (size_t)tile * 16 * 256;
        const int node0 = tile * 16;
        int b0 = 0, b15 = 0;
        if (do_pool) { b0 = batch[node0]; b15 = batch[node0 + 15]; }
        h16x8 afrag[4];
#pragma unroll
        for (int kk = 0; kk < 4; kk++)
            afrag[kk] = *(const h16x8*)(arow + m * 256 + kk * 64 + t * 16);
#pragma unroll
        for (int nt = 0; nt < 4; nt++) {
            f32x4 c = {0.f, 0.f, 0.f, 0.f};
#pragma unroll
            for (int kk = 0; kk < 4; kk++)
                c = __builtin_amdgcn_mfma_f32_16x16x32_f16(afrag[kk], bfrag[nt][kk], c, 0, 0, 0);
            float ov[4];
#pragma unroll
            for (int r = 0; r < 4; r++) {
                ov[r] = fmaxf(c[r] + bb[nt], 0.0f);
                *(h16*)(arow + (t * 4 + r) * 256 + (nt * 16 + m) * 2) = (h16)ov[r];
            }
            if (do_pool) {
                if (b0 == b15) {
                    float mx = fmaxf(fmaxf(ov[0], ov[1]), fmaxf(ov[2], ov[3]));
                    mx = fmaxf(mx, __shfl_xor(mx, 16));
                    mx = fmaxf(mx, __shfl_xor(mx, 32));
                    if (t == 0)
                        atomicMax(&g[b0 * HDIM + nt * 16 + m], __float_as_uint(mx));
                } else {
#pragma unroll
                    for (int r = 0; r < 4; r++)
                        atomicMax(&g[batch[node0 + t * 4 + r] * HDIM + nt * 16 + m],
                                  __float_as_uint(ov[r]));
                }
            }
        }
    }
}

// -------------------------------------------------------------------- MLP head
__global__ __launch_bounds__(64) void mlp_kernel(const unsigned* __restrict__ g,
                                                 const float* __restrict__ wl1,
                                                 const float* __restrict__ bl1,
                                                 const float* __restrict__ wl2,
                                                 const float* __restrict__ bl2,
                                                 float* __restrict__ out) {
    int t = threadIdx.x;   // graph index, one block of 64
    float gv[HDIM];
#pragma unroll
    for (int k = 0; k < HDIM; k++) gv[k] = __uint_as_float(g[t * HDIM + k]);
    float o = bl2[0];
#pragma unroll
    for (int j = 0; j < 5; j++) {
        float hj = bl1[j];
#pragma unroll
        for (int k = 0; k < HDIM; k++) hj += gv[k] * wl1[k * 5 + j];
        hj = fmaxf(hj, 0.0f);
        o += hj * wl2[j];
    }
    out[t] = o;
}

// ------------------------------------------------------------------- launch
extern "C" void kernel_launch(void* const* d_in, const int* in_sizes, int n_in,
                              void* d_out, int out_size, void* d_ws, size_t ws_size,
                              hipStream_t stream) {
    const float* x   = (const float*)d_in[0];
    const int*   ei  = (const int*)d_in[1];
    const int*   bat = (const int*)d_in[2];
    const float* w1s = (const float*)d_in[3];
    const float* b1s = (const float*)d_in[4];
    const float* w1d = (const float*)d_in[5];
    const float* b1d = (const float*)d_in[6];
    const float* w2s = (const float*)d_in[7];
    const float* b2s = (const float*)d_in[8];
    const float* w2d = (const float*)d_in[9];
    const float* b2d = (const float*)d_in[10];
    const float* w3s = (const float*)d_in[11];
    const float* b3s = (const float*)d_in[12];
    const float* w3d = (const float*)d_in[13];
    const float* b3d = (const float*)d_in[14];
    const float* wl1 = (const float*)d_in[15];
    const float* bl1 = (const float*)d_in[16];
    const float* wl2 = (const float*)d_in[17];
    const float* bl2 = (const float*)d_in[18];
    float* out = (float*)d_out;

    // Workspace. bufP (25.6MB) aliases bktA|bktT (packed ints, dead before
    // layer-1 agg). bufQ (25.6MB): first half doubles as xh.
    char* p = (char*)d_ws;
    int*   deg_out = (int*)p;              p += N_NODES * 4;
    int*   deg_in  = (int*)p;              p += N_NODES * 4;
    int*   rowptrP = (int*)p;              p += N_NODES * 4;
    int*   colptrP = (int*)p;              p += N_NODES * 4;
    float* r_out   = (float*)p;            p += N_NODES * 4;
    float* r_in    = (float*)p;            p += N_NODES * 4;
    int*   cntTabA = (int*)p;              p += (size_t)NB * NBLK * 4;
    int*   cntTabT = (int*)p;              p += (size_t)NB * NBLK * 4;
    int*   totTab  = (int*)p;              p += 1024 * 4;
    int*   bktStartA = (int*)p;            p += 512 * 4;
    int*   bktStartT = (int*)p;            p += 512 * 4;
    int*   recA    = (int*)p;              p += (size_t)EPAD * 4;
    int*   recT    = (int*)p;              p += (size_t)EPAD * 4;
    char*  bufP    = p;                    // 25.6MB: bktA | bktT during prep
    int*   bktA    = (int*)p;
    int*   bktT    = (int*)(p + (size_t)N_EDGES * 4);
    p += 2 * (size_t)N_EDGES * 8;
    char*  bufQ    = p;                    // 25.6MB: xh in first half
    h16*   xh      = (h16*)p;
    p += 2 * (size_t)N_EDGES * 8;
    unsigned* g    = (unsigned*)p;         p += NGRAPH * HDIM * 4;
    h16*   WT      = (h16*)p;              p += 3 * 8192 * 2;
    float* bc      = (float*)p;            p += 3 * 64 * 4;

    cast_kernel<<<(N_NODES * 16 + 255) / 256, 256, 0, stream>>>(
        (const float4*)x, (h16x4*)xh, g);
    dim3 gw(32, 3);
    wprep_kernel<<<gw, 256, 0, stream>>>(w1s, w1d, w2s, w2d, w3s, w3d,
                                         b1s, b1d, b2s, b2d, b3s, b3d, WT, bc);

    bucket_count<<<NBLK, 512, 0, stream>>>(ei, cntTabA, cntTabT);
    dim3 gb2(NB, 2);
    chunk_scan<<<gb2, 256, 0, stream>>>(cntTabA, cntTabT, totTab);
    start_scan<<<1, 512, 0, stream>>>(totTab, bktStartA, bktStartT);
    bucketize_write<<<NBLK, 512, 0, stream>>>(ei, cntTabA, cntTabT,
                                              bktStartA, bktStartT, bktA, bktT);

    dim3 gb(NB, 2);
    bucket_deg_scatter<<<gb, 256, 0, stream>>>(bktStartA, bktStartT, bktA, bktT,
                                               deg_out, deg_in, r_out, r_in,
                                               rowptrP, colptrP, recA, recT);

    const int agrid = N_NODES * 2 / 4;    // one wave per (node,dir), 4 waves/block
    // Layer 1: xh (128B rows, sh2=7) -> bufP
    agg_kernel<<<agrid, 256, 0, stream>>>((const char*)xh, bufP, 7,
                                          rowptrP, deg_out, recA, colptrP, deg_in, recT,
                                          r_out, r_in);
    gemm_kernel<<<256, 256, 0, stream>>>(bufP, WT, bc, bat, g, 0);
    // Layer 2: bufP (256B rows, sh2=8) -> bufQ
    agg_kernel<<<agrid, 256, 0, stream>>>(bufP, bufQ, 8,
                                          rowptrP, deg_out, recA, colptrP, deg_in, recT,
                                          r_out, r_in);
    gemm_kernel<<<256, 256, 0, stream>>>(bufQ, WT + 8192, bc + 64, bat, g, 0);
    // Layer 3: bufQ -> bufP, fused max-pool
    agg_kernel<<<agrid, 256, 0, stream>>>(bufQ, bufP, 8,
                                          rowptrP, deg_out, recA, colptrP, deg_in, recT,
                                          r_out, r_in);
    gemm_kernel<<<256, 256, 0, stream>>>(bufP, WT + 16384, bc + 128, bat, g, 1);

    mlp_kernel<<<1, 64, 0, stream>>>(g, wl1, bl1, wl2, bl2, out);
}

// Round 9
// 559.229 us; speedup vs baseline: 1.0083x; 1.0083x over previous
//
#include <hip/hip_runtime.h>

// Problem constants
#define N_NODES 100000
#define N_EDGES 1600000
#define HDIM    64
#define NGRAPH  64
#define BW      256                      // bucket width (nodes); shift = 8
#define NB      391                      // ceil(N_NODES / BW)
#define PADS    260                      // per-bucket rec slack (align2 + pad2/node)
#define EPAD    (N_EDGES + NB * PADS + 16) // rec capacity (int2 records)
#define NBLK    256                      // edge-pass blocks
#define CHUNK   ((N_EDGES + NBLK - 1) / NBLK)
#define MTILES  (N_NODES / 16)           // 6250 GEMM m-tiles

// native fp16, no hip_fp16 header
typedef _Float16 h16;
typedef _Float16 h16x4 __attribute__((ext_vector_type(4)));
typedef _Float16 h16x8 __attribute__((ext_vector_type(8)));
typedef float    f32x4 __attribute__((ext_vector_type(4)));

// ----------------------------------------- K1: per-(block,bucket) edge counts
__global__ __launch_bounds__(512) void bucket_count(const int* __restrict__ ei,
                                                    int* __restrict__ cntTabA,
                                                    int* __restrict__ cntTabT) {
    __shared__ int cA[NB], cT[NB];
    const int tid = threadIdx.x;
    for (int i = tid; i < NB; i += 512) { cA[i] = 0; cT[i] = 0; }
    __syncthreads();
    const int e0 = blockIdx.x * CHUNK, e1 = min(e0 + CHUNK, N_EDGES);
    for (int e = e0 + tid; e < e1; e += 512) {
        int r = ei[e];
        int c = ei[N_EDGES + e];
        atomicAdd(&cA[r >> 8], 1);
        atomicAdd(&cT[c >> 8], 1);
    }
    __syncthreads();
    for (int b = tid; b < NB; b += 512) {
        cntTabA[b * NBLK + blockIdx.x] = cA[b];
        cntTabT[b * NBLK + blockIdx.x] = cT[b];
    }
}

// ---------------- K2a: per-bucket LDS scan of the 256 per-block counts
__global__ __launch_bounds__(256) void chunk_scan(int* __restrict__ cntTabA,
                                                  int* __restrict__ cntTabT,
                                                  int* __restrict__ tot) {
    __shared__ int s[256];
    const int b = blockIdx.x, d = blockIdx.y, tid = threadIdx.x;
    int* tab = d ? cntTabT : cntTabA;
    int v = tab[b * NBLK + tid];
    s[tid] = v;
    __syncthreads();
    for (int off = 1; off < 256; off <<= 1) {
        int t = (tid >= off) ? s[tid - off] : 0;
        __syncthreads();
        s[tid] += t;
        __syncthreads();
    }
    tab[b * NBLK + tid] = s[tid] - v;       // exclusive within bucket
    if (tid == 255) tot[d * 512 + b] = s[255];
}

// ---------------- K2b: bucket-start scan (both dirs, one block, parallel)
__global__ __launch_bounds__(512) void start_scan(const int* __restrict__ tot,
                                                  int* __restrict__ bktStartA,
                                                  int* __restrict__ bktStartT) {
    __shared__ int s[512];
    const int tid = threadIdx.x;
    int v = (tid < NB) ? tot[tid] : 0;
    s[tid] = v;
    __syncthreads();
    for (int off = 1; off < 512; off <<= 1) {
        int t = (tid >= off) ? s[tid - off] : 0;
        __syncthreads();
        s[tid] += t;
        __syncthreads();
    }
    if (tid < NB) bktStartA[tid] = s[tid] - v;
    if (tid == 0) bktStartA[NB] = N_EDGES;
    __syncthreads();
    int v2 = (tid < NB) ? tot[512 + tid] : 0;
    s[tid] = v2;
    __syncthreads();
    for (int off = 1; off < 512; off <<= 1) {
        int t = (tid >= off) ? s[tid - off] : 0;
        __syncthreads();
        s[tid] += t;
        __syncthreads();
    }
    if (tid < NB) bktStartT[tid] = s[tid] - v2;
    if (tid == 0) bktStartT[NB] = N_EDGES;
}

// --------------------------- K3: bucketize write (bases pre-reserved)
// packed 4B entries: (src << 8) | (tgt & 255)  — halves write traffic
__global__ __launch_bounds__(512) void bucketize_write(const int* __restrict__ ei,
                                                       const int* __restrict__ cntTabA,
                                                       const int* __restrict__ cntTabT,
                                                       const int* __restrict__ bktStartA,
                                                       const int* __restrict__ bktStartT,
                                                       int* __restrict__ bktA,
                                                       int* __restrict__ bktT) {
    __shared__ int bA[NB], bT[NB];
    const int tid = threadIdx.x;
    for (int i = tid; i < NB; i += 512) {
        bA[i] = bktStartA[i] + cntTabA[i * NBLK + blockIdx.x];
        bT[i] = bktStartT[i] + cntTabT[i * NBLK + blockIdx.x];
    }
    __syncthreads();
    const int e0 = blockIdx.x * CHUNK, e1 = min(e0 + CHUNK, N_EDGES);
    for (int e = e0 + tid; e < e1; e += 512) {
        int r = ei[e];
        int c = ei[N_EDGES + e];
        int pA = atomicAdd(&bA[r >> 8], 1);
        bktA[pA] = (c << 8) | (r & 255);     // tgt=r, src=c
        int pT = atomicAdd(&bT[c >> 8], 1);
        bktT[pT] = (r << 8) | (c & 255);     // tgt=c, src=r
    }
}

// ----- K4 (merged): degrees + rsqrt + padded ptrs + counting scatter.
// One kernel per (bucket, dir): count -> scan -> scatter; the second bkt
// pass hits L2 (bucket ~16KB). rec base for bucket b = align2(bktStart[b])
// + b*PADS so int2 regions are int4-aligned (pad2 <= 1/node).
// Records embed the weight: (src<<7, w fp32 bits) — no gather in agg.
__global__ __launch_bounds__(256) void bucket_deg_scatter(
        const int* __restrict__ bktStartA, const int* __restrict__ bktStartT,
        const int* __restrict__ bktA, const int* __restrict__ bktT,
        const float* __restrict__ r_out_t, const float* __restrict__ r_in_t,
        int* __restrict__ deg_out, int* __restrict__ deg_in,
        float* __restrict__ r_out, float* __restrict__ r_in,
        int* __restrict__ rowptrP, int* __restrict__ colptrP,
        int2* __restrict__ recA, int2* __restrict__ recT) {
    __shared__ int c[BW];
    __shared__ int sc[256];
    __shared__ float rwt[BW];
    const int b = blockIdx.x, d = blockIdx.y, tid = threadIdx.x;
    const int* bs = d ? bktStartT : bktStartA;
    const int* bkt = d ? bktT : bktA;
    int* deg = d ? deg_in : deg_out;
    float* rr = d ? r_in : r_out;
    const float* rsrc = d ? r_out_t : r_in_t;   // src-side table (gathered)
    int* ptr = d ? colptrP : rowptrP;
    int2* rec = d ? recT : recA;
    const int node0 = b * BW;
    c[tid] = 0;
    __syncthreads();
    const int i0 = bs[b], i1 = bs[b + 1];
    for (int i = i0 + tid; i < i1; i += 256) atomicAdd(&c[bkt[i] & 255], 1);
    __syncthreads();
    const int n = node0 + tid;
    int dg = c[tid];
    int pad = (n < N_NODES) ? (dg + (dg & 1)) : 0;
    float myr = (n < N_NODES && dg > 0) ? rsqrtf((float)dg) : 0.0f;
    if (n < N_NODES) {
        deg[n] = dg;
        rr[n] = myr;
    }
    rwt[tid] = myr;                          // target-side factor, bucket-local
    sc[tid] = pad;
    __syncthreads();
    for (int off = 1; off < 256; off <<= 1) {
        int t = (tid >= off) ? sc[tid - off] : 0;
        __syncthreads();
        sc[tid] += t;
        __syncthreads();
    }
    const int recBase = ((i0 + 1) & ~1) + b * PADS;
    int myStart = recBase + (sc[tid] - pad);
    if (n < N_NODES) ptr[n] = myStart;
    c[tid] = myStart;                        // cur cursor
    __syncthreads();
    for (int i = i0 + tid; i < i1; i += 256) {
        int e = bkt[i];
        int src = e >> 8, tl = e & 255;
        float w = rwt[tl] * rsrc[src];
        int p = atomicAdd(&c[tl], 1);
        rec[p] = make_int2(src << 7, __float_as_int(w));
    }
}

// -- K0b: src-side rsqrt tables must exist before the scatter pass gathers
// them; computed from a dedicated degree count over ei (L2-resident atomics
// were measured cheap in deg-table form? No — reuse bucket path: this kernel
// derives r tables from the merged kernel's own pass-1 ordering hazard, so
// instead we run the merged kernel twice logically. Simpler: a tiny kernel
// that converts deg->r after a first counting-only pass is avoided by
// splitting: pass 1 (count+tables) for BOTH dirs, then pass 2 (scatter).
// See bucket_deg_tab + bucket_scatter2 below; bucket_deg_scatter above is
// unused for dir-crossed weights. (Kept compiled-out via dead code is
// avoided: we simply don't launch it.)

// ----- K4a: degrees + rsqrt + padded node ptrs (per bucket, per dir)
__global__ __launch_bounds__(256) void bucket_deg_tab(
        const int* __restrict__ bktStartA, const int* __restrict__ bktStartT,
        const int* __restrict__ bktA, const int* __restrict__ bktT,
        int* __restrict__ deg_out, int* __restrict__ deg_in,
        float* __restrict__ r_out, float* __restrict__ r_in,
        int* __restrict__ rowptrP, int* __restrict__ colptrP) {
    __shared__ int c[BW];
    __shared__ int sc[256];
    const int b = blockIdx.x, d = blockIdx.y, tid = threadIdx.x;
    const int* bs = d ? bktStartT : bktStartA;
    const int* bkt = d ? bktT : bktA;
    int* deg = d ? deg_in : deg_out;
    float* rr = d ? r_in : r_out;
    int* ptr = d ? colptrP : rowptrP;
    const int node0 = b * BW;
    c[tid] = 0;
    __syncthreads();
    const int i0 = bs[b], i1 = bs[b + 1];
    for (int i = i0 + tid; i < i1; i += 256) atomicAdd(&c[bkt[i] & 255], 1);
    __syncthreads();
    const int n = node0 + tid;
    int dg = c[tid];
    int pad = (n < N_NODES) ? (dg + (dg & 1)) : 0;
    if (n < N_NODES) {
        deg[n] = dg;
        rr[n] = dg > 0 ? rsqrtf((float)dg) : 0.0f;
    }
    sc[tid] = pad;
    __syncthreads();
    for (int off = 1; off < 256; off <<= 1) {
        int t = (tid >= off) ? sc[tid - off] : 0;
        __syncthreads();
        sc[tid] += t;
        __syncthreads();
    }
    const int recBase = ((i0 + 1) & ~1) + b * PADS;
    if (n < N_NODES) ptr[n] = recBase + (sc[tid] - pad);
}

// ----- K4b: counting scatter with embedded weights (bkt pass 2, L2-hot)
__global__ __launch_bounds__(256) void bucket_scatter2(
        const int* __restrict__ bktStartA, const int* __restrict__ bktStartT,
        const int* __restrict__ bktA, const int* __restrict__ bktT,
        const int* __restrict__ rowptrP, const int* __restrict__ colptrP,
        const float* __restrict__ r_out, const float* __restrict__ r_in,
        int2* __restrict__ recA, int2* __restrict__ recT) {
    __shared__ int cur[BW];
    __shared__ float rwt[BW];
    const int b = blockIdx.x, d = blockIdx.y, tid = threadIdx.x;
    const int* bs = d ? bktStartT : bktStartA;
    const int* bkt = d ? bktT : bktA;
    const int* ptr = d ? colptrP : rowptrP;
    const float* rt = d ? r_in : r_out;      // target-side (bucket-local)
    const float* rs = d ? r_out : r_in;      // source-side (gathered)
    int2* rec = d ? recT : recA;
    const int node0 = b * BW;
    {
        int n = node0 + tid;
        cur[tid] = (n < N_NODES) ? ptr[n] : 0;
        rwt[tid] = (n < N_NODES) ? rt[n] : 0.0f;
    }
    __syncthreads();
    const int i0 = bs[b], i1 = bs[b + 1];
    for (int i = i0 + tid; i < i1; i += 256) {
        int e = bkt[i];
        int src = e >> 8, tl = e & 255;
        float w = rwt[tl] * rs[src];
        int p = atomicAdd(&cur[tl], 1);
        rec[p] = make_int2(src << 7, __float_as_int(w));
    }
}

// ---------------------------------------- x -> fp16 cast (+ zero pooled g)
__global__ __launch_bounds__(256) void cast_kernel(const float4* __restrict__ x,
                                                   h16x4* __restrict__ xh,
                                                   unsigned* __restrict__ g) {
    if (blockIdx.x == 0) {
        for (int j = threadIdx.x; j < NGRAPH * HDIM; j += 256) g[j] = 0u;
    }
    int i = blockIdx.x * 256 + threadIdx.x;   // over N*64/4 float4s
    if (i < N_NODES * 16) {
        float4 v = x[i];
        h16x4 o;
        o.x = (h16)v.x; o.y = (h16)v.y; o.z = (h16)v.z; o.w = (h16)v.w;
        xh[i] = o;
    }
}

// ------------------------- weight prep: WT[l][f][k] = 0.5*Wcat^T fp16, bcat
__global__ __launch_bounds__(256) void wprep_kernel(
        const float* __restrict__ w1s, const float* __restrict__ w1d,
        const float* __restrict__ w2s, const float* __restrict__ w2d,
        const float* __restrict__ w3s, const float* __restrict__ w3d,
        const float* __restrict__ b1s, const float* __restrict__ b1d,
        const float* __restrict__ b2s, const float* __restrict__ b2d,
        const float* __restrict__ b3s, const float* __restrict__ b3d,
        h16* __restrict__ WT, float* __restrict__ bc) {
    const int l = blockIdx.y;
    const float* ws = l == 0 ? w1s : l == 1 ? w2s : w3s;
    const float* wd = l == 0 ? w1d : l == 1 ? w2d : w3d;
    int e = blockIdx.x * 256 + threadIdx.x;
    if (e < 8192) {
        int f = e >> 7, k = e & 127;
        float v = (k < 64) ? ws[k * 64 + f] : wd[(k - 64) * 64 + f];
        WT[l * 8192 + f * 128 + k] = (h16)(0.5f * v);
    }
    if (blockIdx.x == 0 && threadIdx.x < 64) {
        const float* bs = l == 0 ? b1s : l == 1 ? b2s : b3s;
        const float* bd = l == 0 ? b1d : l == 1 ? b2d : b3d;
        bc[l * 64 + threadIdx.x] = 0.5f * (bs[threadIdx.x] + bd[threadIdx.x]);
    }
}

// ------------------------------------------------ aggregation (LDS-free)
__device__ __forceinline__ void fma4h(float4& a, float w, h16x4 f) {
    a.x = fmaf(w, (float)f.x, a.x);
    a.y = fmaf(w, (float)f.y, a.y);
    a.z = fmaf(w, (float)f.z, a.z);
    a.w = fmaf(w, (float)f.w, a.w);
}

__device__ __forceinline__ float4 red_s(float4 v) {
    v.x += __shfl_xor(v.x, 16); v.y += __shfl_xor(v.y, 16);
    v.z += __shfl_xor(v.z, 16); v.w += __shfl_xor(v.w, 16);
    v.x += __shfl_xor(v.x, 32); v.y += __shfl_xor(v.y, 32);
    v.z += __shfl_xor(v.z, 32); v.w += __shfl_xor(v.w, 32);
    return v;
}

__device__ __forceinline__ h16x4 ld_h4(const char* __restrict__ p) {
    return *(const h16x4*)p;
}

// per-wave aggregation; lane (q,s): q = feature quad, s = edge-pair slot.
// records hold src<<7; sh=0 for 128B rows (xh), sh=1 for 256B rows (acc/h).
__device__ __forceinline__ float4 agg_dir(const char* __restrict__ hb,
                                          const int2* __restrict__ rec,
                                          int start, int deg, int q, int s, int sh) {
    float4 a0 = {0.f,0.f,0.f,0.f}, a1 = {0.f,0.f,0.f,0.f};
    float4 a2 = {0.f,0.f,0.f,0.f}, a3 = {0.f,0.f,0.f,0.f};
    const int4* rec4 = (const int4*)(rec + start);
    const int qb = q * 8;
    int k = 0;
    for (; k + 16 <= deg; k += 16) {
        int4 p0 = rec4[(k >> 1) + s];
        int4 p1 = rec4[(k >> 1) + 4 + s];
        h16x4 f0 = ld_h4(hb + (p0.x << sh) + qb);
        h16x4 f1 = ld_h4(hb + (p0.z << sh) + qb);
        h16x4 f2 = ld_h4(hb + (p1.x << sh) + qb);
        h16x4 f3 = ld_h4(hb + (p1.z << sh) + qb);
        fma4h(a0, __int_as_float(p0.y), f0);
        fma4h(a1, __int_as_float(p0.w), f1);
        fma4h(a2, __int_as_float(p1.y), f2);
        fma4h(a3, __int_as_float(p1.w), f3);
    }
    if (k + 8 <= deg) {
        int4 p = rec4[(k >> 1) + s];
        h16x4 f0 = ld_h4(hb + (p.x << sh) + qb);
        h16x4 f1 = ld_h4(hb + (p.z << sh) + qb);
        fma4h(a0, __int_as_float(p.y), f0);
        fma4h(a1, __int_as_float(p.w), f1);
        k += 8;
    }
    int r = deg - k;
    if (2 * s < r) {
        int4 p = rec4[(k >> 1) + s];
        h16x4 f0 = ld_h4(hb + (p.x << sh) + qb);
        fma4h(a2, __int_as_float(p.y), f0);
        if (2 * s + 1 < r) {
            h16x4 f1 = ld_h4(hb + (p.z << sh) + qb);
            fma4h(a3, __int_as_float(p.w), f1);
        }
    }
    a0.x += a1.x; a0.y += a1.y; a0.z += a1.z; a0.w += a1.w;
    a2.x += a3.x; a2.y += a3.y; a2.z += a3.z; a2.w += a3.w;
    a0.x += a2.x; a0.y += a2.y; a0.z += a2.z; a0.w += a2.w;
    return red_s(a0);
}

// no LDS, no barrier: one wave per (node, dir); dirs write disjoint halves.
__global__ __launch_bounds__(256) void agg_kernel(
        const char* __restrict__ h_in, char* __restrict__ acc_out, int sh,
        const int* __restrict__ rowptrP, const int* __restrict__ deg_out,
        const int2* __restrict__ recA,
        const int* __restrict__ colptrP, const int* __restrict__ deg_in,
        const int2* __restrict__ recT) {
    const int tid  = threadIdx.x;
    const int wid  = (blockIdx.x << 2) + (tid >> 6);   // global wave id
    const int lane = tid & 63;
    const int node = wid >> 1;
    const int dir  = wid & 1;
    const int q = lane & 15;
    const int s = lane >> 4;

    const int* ptr = dir ? colptrP : rowptrP;
    const int* deg = dir ? deg_in : deg_out;
    const int2* rec = dir ? recT : recA;

    float4 a = agg_dir(h_in, rec, ptr[node], deg[node], q, s, sh);
    if (s == 0) {
        h16x4 pk;
        pk.x = (h16)a.x; pk.y = (h16)a.y; pk.z = (h16)a.z; pk.w = (h16)a.w;
        *(h16x4*)(acc_out + (size_t)node * 256 + dir * 128 + q * 8) = pk;
    }
}

// --------------------------------------- GEMM via MFMA, h written in place
// acc rows are 256B ([128] fp16); h = ReLU(acc @ WT^T + bc) written into the
// first 128B of each row. Optional fused max-pool (layer 3): batch is sorted,
// so most 16-node tiles map to one graph -> shfl-reduce + 1 atomic per feat.
__global__ __launch_bounds__(256) void gemm_kernel(char* __restrict__ acc,
                                                   const h16* __restrict__ WT,
                                                   const float* __restrict__ bc,
                                                   const int* __restrict__ batch,
                                                   unsigned* __restrict__ g,
                                                   int do_pool) {
    const int lane = threadIdx.x & 63;
    const int wid = (blockIdx.x * 256 + threadIdx.x) >> 6;
    const int nW = gridDim.x * 4;
    const int m = lane & 15, t = lane >> 4;

    h16x8 bfrag[4][4];
    float bb[4];
#pragma unroll
    for (int nt = 0; nt < 4; nt++) {
        bb[nt] = bc[nt * 16 + m];
#pragma unroll
        for (int kk = 0; kk < 4; kk++)
            bfrag[nt][kk] = *(const h16x8*)(WT + (nt * 16 + m) * 128 + kk * 32 + t * 8);
    }

    for (int tile = wid; tile < MTILES; tile += nW) {
        char* arow = acc + (size_t)tile * 16 * 256;
        const int node0 = tile * 16;
        int b0 = 0, b15 = 0;
        if (do_pool) { b0 = batch[node0]; b15 = batch[node0 + 15]; }
        h16x8 afrag[4];
#pragma unroll
        for (int kk = 0; kk < 4; kk++)
            afrag[kk] = *(const h16x8*)(arow + m * 256 + kk * 64 + t * 16);
#pragma unroll
        for (int nt = 0; nt < 4; nt++) {
            f32x4 c = {0.f, 0.f, 0.f, 0.f};
#pragma unroll
            for (int kk = 0; kk < 4; kk++)
                c = __builtin_amdgcn_mfma_f32_16x16x32_f16(afrag[kk], bfrag[nt][kk], c, 0, 0, 0);
            float ov[4];
#pragma unroll
            for (int r = 0; r < 4; r++) {
                ov[r] = fmaxf(c[r] + bb[nt], 0.0f);
                *(h16*)(arow + (t * 4 + r) * 256 + (nt * 16 + m) * 2) = (h16)ov[r];
            }
            if (do_pool) {
                if (b0 == b15) {
                    float mx = fmaxf(fmaxf(ov[0], ov[1]), fmaxf(ov[2], ov[3]));
                    mx = fmaxf(mx, __shfl_xor(mx, 16));
                    mx = fmaxf(mx, __shfl_xor(mx, 32));
                    if (t == 0)
                        atomicMax(&g[b0 * HDIM + nt * 16 + m], __float_as_uint(mx));
                } else {
#pragma unroll
                    for (int r = 0; r < 4; r++)
                        atomicMax(&g[batch[node0 + t * 4 + r] * HDIM + nt * 16 + m],
                                  __float_as_uint(ov[r]));
                }
            }
        }
    }
}

// -------------------------------------------------------------------- MLP head
__global__ __launch_bounds__(64) void mlp_kernel(const unsigned* __restrict__ g,
                                                 const float* __restrict__ wl1,
                                                 const float* __restrict__ bl1,
                                                 const float* __restrict__ wl2,
                                                 const float* __restrict__ bl2,
                                                 float* __restrict__ out) {
    int t = threadIdx.x;   // graph index, one block of 64
    float gv[HDIM];
#pragma unroll
    for (int k = 0; k < HDIM; k++) gv[k] = __uint_as_float(g[t * HDIM + k]);
    float o = bl2[0];
#pragma unroll
    for (int j = 0; j < 5; j++) {
        float hj = bl1[j];
#pragma unroll
        for (int k = 0; k < HDIM; k++) hj += gv[k] * wl1[k * 5 + j];
        hj = fmaxf(hj, 0.0f);
        o += hj * wl2[j];
    }
    out[t] = o;
}

// ------------------------------------------------------------------- launch
extern "C" void kernel_launch(void* const* d_in, const int* in_sizes, int n_in,
                              void* d_out, int out_size, void* d_ws, size_t ws_size,
                              hipStream_t stream) {
    const float* x   = (const float*)d_in[0];
    const int*   ei  = (const int*)d_in[1];
    const int*   bat = (const int*)d_in[2];
    const float* w1s = (const float*)d_in[3];
    const float* b1s = (const float*)d_in[4];
    const float* w1d = (const float*)d_in[5];
    const float* b1d = (const float*)d_in[6];
    const float* w2s = (const float*)d_in[7];
    const float* b2s = (const float*)d_in[8];
    const float* w2d = (const float*)d_in[9];
    const float* b2d = (const float*)d_in[10];
    const float* w3s = (const float*)d_in[11];
    const float* b3s = (const float*)d_in[12];
    const float* w3d = (const float*)d_in[13];
    const float* b3d = (const float*)d_in[14];
    const float* wl1 = (const float*)d_in[15];
    const float* bl1 = (const float*)d_in[16];
    const float* wl2 = (const float*)d_in[17];
    const float* bl2 = (const float*)d_in[18];
    float* out = (float*)d_out;

    // Workspace. bufP (25.6MB) aliases bktA|bktT (packed 4B, dead before
    // layer-1 agg). bufQ (25.6MB): first half doubles as xh.
    char* p = (char*)d_ws;
    int*   deg_out = (int*)p;              p += N_NODES * 4;
    int*   deg_in  = (int*)p;              p += N_NODES * 4;
    int*   rowptrP = (int*)p;              p += N_NODES * 4;
    int*   colptrP = (int*)p;              p += N_NODES * 4;
    float* r_out   = (float*)p;            p += N_NODES * 4;
    float* r_in    = (float*)p;            p += N_NODES * 4;
    int*   cntTabA = (int*)p;              p += (size_t)NB * NBLK * 4;
    int*   cntTabT = (int*)p;              p += (size_t)NB * NBLK * 4;
    int*   totTab  = (int*)p;              p += 1024 * 4;
    int*   bktStartA = (int*)p;            p += 512 * 4;
    int*   bktStartT = (int*)p;            p += 512 * 4;
    int2*  recA    = (int2*)p;             p += (size_t)EPAD * 8;
    int2*  recT    = (int2*)p;             p += (size_t)EPAD * 8;
    char*  bufP    = p;                    // 25.6MB: bktA | bktT during prep
    int*   bktA    = (int*)p;
    int*   bktT    = (int*)(p + (size_t)N_EDGES * 4);
    p += 2 * (size_t)N_EDGES * 8;
    char*  bufQ    = p;                    // 25.6MB: xh in first half
    h16*   xh      = (h16*)p;
    p += 2 * (size_t)N_EDGES * 8;
    unsigned* g    = (unsigned*)p;         p += NGRAPH * HDIM * 4;
    h16*   WT      = (h16*)p;              p += 3 * 8192 * 2;
    float* bc      = (float*)p;            p += 3 * 64 * 4;

    cast_kernel<<<(N_NODES * 16 + 255) / 256, 256, 0, stream>>>(
        (const float4*)x, (h16x4*)xh, g);
    dim3 gw(32, 3);
    wprep_kernel<<<gw, 256, 0, stream>>>(w1s, w1d, w2s, w2d, w3s, w3d,
                                         b1s, b1d, b2s, b2d, b3s, b3d, WT, bc);

    bucket_count<<<NBLK, 512, 0, stream>>>(ei, cntTabA, cntTabT);
    dim3 gb2(NB, 2);
    chunk_scan<<<gb2, 256, 0, stream>>>(cntTabA, cntTabT, totTab);
    start_scan<<<1, 512, 0, stream>>>(totTab, bktStartA, bktStartT);
    bucketize_write<<<NBLK, 512, 0, stream>>>(ei, cntTabA, cntTabT,
                                              bktStartA, bktStartT, bktA, bktT);

    dim3 gb(NB, 2);
    bucket_deg_tab<<<gb, 256, 0, stream>>>(bktStartA, bktStartT, bktA, bktT,
                                           deg_out, deg_in, r_out, r_in,
                                           rowptrP, colptrP);
    bucket_scatter2<<<gb, 256, 0, stream>>>(bktStartA, bktStartT, bktA, bktT,
                                            rowptrP, colptrP, r_out, r_in,
                                            recA, recT);

    const int agrid = N_NODES * 2 / 4;    // one wave per (node,dir), 4 waves/block
    // Layer 1: xh (128B rows) -> bufP
    agg_kernel<<<agrid, 256, 0, stream>>>((const char*)xh, bufP, 0,
                                          rowptrP, deg_out, recA, colptrP, deg_in, recT);
    gemm_kernel<<<256, 256, 0, stream>>>(bufP, WT, bc, bat, g, 0);
    // Layer 2: bufP (256B rows) -> bufQ
    agg_kernel<<<agrid, 256, 0, stream>>>(bufP, bufQ, 1,
                                          rowptrP, deg_out, recA, colptrP, deg_in, recT);
    gemm_kernel<<<256, 256, 0, stream>>>(bufQ, WT + 8192, bc + 64, bat, g, 0);
    // Layer 3: bufQ -> bufP, fused max-pool
    agg_kernel<<<agrid, 256, 0, stream>>>(bufQ, bufP, 1,
                                          rowptrP, deg_out, recA, colptrP, deg_in, recT);
    gemm_kernel<<<256, 256, 0, stream>>>(bufP, WT + 16384, bc + 128, bat, g, 1);

    mlp_kernel<<<1, 64, 0, stream>>>(g, wl1, bl1, wl2, bl2, out);
}

// Round 10
// 489.279 us; speedup vs baseline: 1.1524x; 1.1430x over previous
//
#include <hip/hip_runtime.h>

// Problem constants
#define N_NODES 100000
#define N_EDGES 1600000
#define EPAD    (N_EDGES + NB * BW)      // rec capacity w/ per-bucket slack
#define HDIM    64
#define NGRAPH  64
#define BW      256                      // bucket width (nodes); shift = 8
#define NB      391                      // ceil(N_NODES / BW)
#define NBLK    256                      // edge-pass blocks
#define CHUNK   ((N_EDGES + NBLK - 1) / NBLK)
#define MTILES  (N_NODES / 16)           // 6250 GEMM m-tiles

// native fp16, no hip_fp16 header
typedef _Float16 h16;
typedef _Float16 h16x4 __attribute__((ext_vector_type(4)));
typedef _Float16 h16x8 __attribute__((ext_vector_type(8)));
typedef float    f32x4 __attribute__((ext_vector_type(4)));

// ----------------------------------------- K1: per-(block,bucket) edge counts
__global__ __launch_bounds__(512) void bucket_count(const int* __restrict__ ei,
                                                    int* __restrict__ cntTabA,
                                                    int* __restrict__ cntTabT) {
    __shared__ int cA[NB], cT[NB];
    const int tid = threadIdx.x;
    for (int i = tid; i < NB; i += 512) { cA[i] = 0; cT[i] = 0; }
    __syncthreads();
    const int e0 = blockIdx.x * CHUNK, e1 = min(e0 + CHUNK, N_EDGES);
    for (int e = e0 + tid; e < e1; e += 512) {
        int r = ei[e];
        int c = ei[N_EDGES + e];
        atomicAdd(&cA[r >> 8], 1);
        atomicAdd(&cT[c >> 8], 1);
    }
    __syncthreads();
    for (int b = tid; b < NB; b += 512) {
        cntTabA[b * NBLK + blockIdx.x] = cA[b];
        cntTabT[b * NBLK + blockIdx.x] = cT[b];
    }
}

// ---------------- K2a: per-bucket LDS scan of the 256 per-block counts
__global__ __launch_bounds__(256) void chunk_scan(int* __restrict__ cntTabA,
                                                  int* __restrict__ cntTabT,
                                                  int* __restrict__ tot) {
    __shared__ int s[256];
    const int b = blockIdx.x, d = blockIdx.y, tid = threadIdx.x;
    int* tab = d ? cntTabT : cntTabA;
    int v = tab[b * NBLK + tid];
    s[tid] = v;
    __syncthreads();
    for (int off = 1; off < 256; off <<= 1) {
        int t = (tid >= off) ? s[tid - off] : 0;
        __syncthreads();
        s[tid] += t;
        __syncthreads();
    }
    tab[b * NBLK + tid] = s[tid] - v;       // exclusive within bucket
    if (tid == 255) tot[d * 512 + b] = s[255];
}

// ---------------- K2b: bucket-start scan (both dirs, one block, parallel)
__global__ __launch_bounds__(512) void start_scan(const int* __restrict__ tot,
                                                  int* __restrict__ bktStartA,
                                                  int* __restrict__ bktStartT) {
    __shared__ int s[512];
    const int tid = threadIdx.x;
    int v = (tid < NB) ? tot[tid] : 0;
    s[tid] = v;
    __syncthreads();
    for (int off = 1; off < 512; off <<= 1) {
        int t = (tid >= off) ? s[tid - off] : 0;
        __syncthreads();
        s[tid] += t;
        __syncthreads();
    }
    if (tid < NB) bktStartA[tid] = s[tid] - v;
    if (tid == 0) bktStartA[NB] = N_EDGES;
    __syncthreads();
    int v2 = (tid < NB) ? tot[512 + tid] : 0;
    s[tid] = v2;
    __syncthreads();
    for (int off = 1; off < 512; off <<= 1) {
        int t = (tid >= off) ? s[tid - off] : 0;
        __syncthreads();
        s[tid] += t;
        __syncthreads();
    }
    if (tid < NB) bktStartT[tid] = s[tid] - v2;
    if (tid == 0) bktStartT[NB] = N_EDGES;
}

// --------------------------- K3: bucketize write (bases pre-reserved)
__global__ __launch_bounds__(512) void bucketize_write(const int* __restrict__ ei,
                                                       const int* __restrict__ cntTabA,
                                                       const int* __restrict__ cntTabT,
                                                       const int* __restrict__ bktStartA,
                                                       const int* __restrict__ bktStartT,
                                                       int2* __restrict__ bktA,
                                                       int2* __restrict__ bktT) {
    __shared__ int bA[NB], bT[NB];
    const int tid = threadIdx.x;
    for (int i = tid; i < NB; i += 512) {
        bA[i] = bktStartA[i] + cntTabA[i * NBLK + blockIdx.x];
        bT[i] = bktStartT[i] + cntTabT[i * NBLK + blockIdx.x];
    }
    __syncthreads();
    const int e0 = blockIdx.x * CHUNK, e1 = min(e0 + CHUNK, N_EDGES);
    for (int e = e0 + tid; e < e1; e += 512) {
        int r = ei[e];
        int c = ei[N_EDGES + e];
        int pA = atomicAdd(&bA[r >> 8], 1);
        bktA[pA] = make_int2(r, c);          // (target, source)
        int pT = atomicAdd(&bT[c >> 8], 1);
        bktT[pT] = make_int2(c, r);          // (target, source)
    }
}

// ----- K4: per-bucket degrees + rsqrt + padded node ptrs (slack allocation)
// rec region for bucket b starts at bktStart[b] + b*BW (pad slack <= BW),
// so node offsets need no cross-bucket scan.
__global__ __launch_bounds__(256) void bucket_deg_ptr(
        const int* __restrict__ bktStartA, const int* __restrict__ bktStartT,
        const int2* __restrict__ bktA, const int2* __restrict__ bktT,
        int* __restrict__ deg_out, int* __restrict__ deg_in,
        float* __restrict__ r_out, float* __restrict__ r_in,
        int* __restrict__ rowptrP, int* __restrict__ colptrP) {
    __shared__ int c[BW];
    __shared__ int s[256];
    const int b = blockIdx.x, d = blockIdx.y, tid = threadIdx.x;
    const int* bs = d ? bktStartT : bktStartA;
    const int2* bkt = d ? bktT : bktA;
    int* deg = d ? deg_in : deg_out;
    float* rr = d ? r_in : r_out;
    int* ptr = d ? colptrP : rowptrP;
    const int node0 = b * BW;
    c[tid] = 0;
    __syncthreads();
    const int i0 = bs[b], i1 = bs[b + 1];
    for (int i = i0 + tid; i < i1; i += 256) atomicAdd(&c[bkt[i].x - node0], 1);
    __syncthreads();
    int n = node0 + tid, dg = c[tid];
    int pad = dg + (dg & 1);
    if (n < N_NODES) {
        deg[n] = dg;
        rr[n] = dg > 0 ? rsqrtf((float)dg) : 0.0f;
    } else pad = 0;
    s[tid] = pad;
    __syncthreads();
    for (int off = 1; off < 256; off <<= 1) {
        int t = (tid >= off) ? s[tid - off] : 0;
        __syncthreads();
        s[tid] += t;
        __syncthreads();
    }
    if (n < N_NODES) ptr[n] = i0 + b * BW + (s[tid] - pad);
}

// ------------------------------------- K7: within-bucket counting scatter
// record payload: (src<<7, w fp32 bits)
__global__ __launch_bounds__(512) void bucket_scatter(
        const int* __restrict__ rowptrP, const int* __restrict__ colptrP,
        const float* __restrict__ r_out, const float* __restrict__ r_in,
        const int* __restrict__ bktStartA, const int* __restrict__ bktStartT,
        const int2* __restrict__ bktA, const int2* __restrict__ bktT,
        int2* __restrict__ recA, int2* __restrict__ recT) {
    __shared__ int cur[BW];
    __shared__ float rwt[BW];
    const int b = blockIdx.x, d = blockIdx.y, tid = threadIdx.x;
    const int* ptr = d ? colptrP : rowptrP;
    const float* rt = d ? r_in : r_out;       // target-side scale (bucket-local)
    const float* rs = d ? r_out : r_in;       // source-side scale (gathered)
    const int* bs = d ? bktStartT : bktStartA;
    const int2* bkt = d ? bktT : bktA;
    int2* rec = d ? recT : recA;
    const int node0 = b * BW;
    if (tid < BW) {
        int n = node0 + tid;
        cur[tid] = (n < N_NODES) ? ptr[n] : 0;
        rwt[tid] = (n < N_NODES) ? rt[n] : 0.0f;
    }
    __syncthreads();
    const int i0 = bs[b], i1 = bs[b + 1];
    for (int i = i0 + tid; i < i1; i += 512) {
        int2 e = bkt[i];
        float w = rwt[e.x - node0] * rs[e.y];
        int p = atomicAdd(&cur[e.x - node0], 1);
        rec[p] = make_int2(e.y << 7, __float_as_int(w));
    }
}

// ---------------------------------------- x -> fp16 cast (+ zero pooled g)
__global__ __launch_bounds__(256) void cast_kernel(const float4* __restrict__ x,
                                                   h16x4* __restrict__ xh,
                                                   unsigned* __restrict__ g) {
    if (blockIdx.x == 0) {
        for (int j = threadIdx.x; j < NGRAPH * HDIM; j += 256) g[j] = 0u;
    }
    int i = blockIdx.x * 256 + threadIdx.x;   // over N*64/4 float4s
    if (i < N_NODES * 16) {
        float4 v = x[i];
        h16x4 o;
        o.x = (h16)v.x; o.y = (h16)v.y; o.z = (h16)v.z; o.w = (h16)v.w;
        xh[i] = o;
    }
}

// ------------------------- weight prep: WT[l][f][k] = 0.5*Wcat^T fp16, bcat
__global__ __launch_bounds__(256) void wprep_kernel(
        const float* __restrict__ w1s, const float* __restrict__ w1d,
        const float* __restrict__ w2s, const float* __restrict__ w2d,
        const float* __restrict__ w3s, const float* __restrict__ w3d,
        const float* __restrict__ b1s, const float* __restrict__ b1d,
        const float* __restrict__ b2s, const float* __restrict__ b2d,
        const float* __restrict__ b3s, const float* __restrict__ b3d,
        h16* __restrict__ WT, float* __restrict__ bc) {
    const int l = blockIdx.y;
    const float* ws = l == 0 ? w1s : l == 1 ? w2s : w3s;
    const float* wd = l == 0 ? w1d : l == 1 ? w2d : w3d;
    int e = blockIdx.x * 256 + threadIdx.x;
    if (e < 8192) {
        int f = e >> 7, k = e & 127;
        float v = (k < 64) ? ws[k * 64 + f] : wd[(k - 64) * 64 + f];
        WT[l * 8192 + f * 128 + k] = (h16)(0.5f * v);
    }
    if (blockIdx.x == 0 && threadIdx.x < 64) {
        const float* bs = l == 0 ? b1s : l == 1 ? b2s : b3s;
        const float* bd = l == 0 ? b1d : l == 1 ? b2d : b3d;
        bc[l * 64 + threadIdx.x] = 0.5f * (bs[threadIdx.x] + bd[threadIdx.x]);
    }
}

// ------------------------------------------------ aggregation (LDS-free)
__device__ __forceinline__ void fma4h(float4& a, float w, h16x4 f) {
    a.x = fmaf(w, (float)f.x, a.x);
    a.y = fmaf(w, (float)f.y, a.y);
    a.z = fmaf(w, (float)f.z, a.z);
    a.w = fmaf(w, (float)f.w, a.w);
}

__device__ __forceinline__ float4 red_s(float4 v) {
    v.x += __shfl_xor(v.x, 16); v.y += __shfl_xor(v.y, 16);
    v.z += __shfl_xor(v.z, 16); v.w += __shfl_xor(v.w, 16);
    v.x += __shfl_xor(v.x, 32); v.y += __shfl_xor(v.y, 32);
    v.z += __shfl_xor(v.z, 32); v.w += __shfl_xor(v.w, 32);
    return v;
}

__device__ __forceinline__ h16x4 ld_h4(const char* __restrict__ p) {
    return *(const h16x4*)p;
}

// per-wave aggregation; lane (q,s): q = feature quad, s = edge-pair slot.
// records hold src<<7; sh=0 for 128B rows (xh), sh=1 for 256B rows (acc/h).
__device__ __forceinline__ float4 agg_dir(const char* __restrict__ hb,
                                          const int2* __restrict__ rec,
                                          int start, int deg, int q, int s, int sh) {
    float4 a0 = {0.f,0.f,0.f,0.f}, a1 = {0.f,0.f,0.f,0.f};
    float4 a2 = {0.f,0.f,0.f,0.f}, a3 = {0.f,0.f,0.f,0.f};
    const int4* rec4 = (const int4*)(rec + start);
    const int qb = q * 8;
    int k = 0;
    for (; k + 16 <= deg; k += 16) {
        int4 p0 = rec4[(k >> 1) + s];
        int4 p1 = rec4[(k >> 1) + 4 + s];
        h16x4 f0 = ld_h4(hb + (p0.x << sh) + qb);
        h16x4 f1 = ld_h4(hb + (p0.z << sh) + qb);
        h16x4 f2 = ld_h4(hb + (p1.x << sh) + qb);
        h16x4 f3 = ld_h4(hb + (p1.z << sh) + qb);
        fma4h(a0, __int_as_float(p0.y), f0);
        fma4h(a1, __int_as_float(p0.w), f1);
        fma4h(a2, __int_as_float(p1.y), f2);
        fma4h(a3, __int_as_float(p1.w), f3);
    }
    if (k + 8 <= deg) {
        int4 p = rec4[(k >> 1) + s];
        h16x4 f0 = ld_h4(hb + (p.x << sh) + qb);
        h16x4 f1 = ld_h4(hb + (p.z << sh) + qb);
        fma4h(a0, __int_as_float(p.y), f0);
        fma4h(a1, __int_as_float(p.w), f1);
        k += 8;
    }
    int r = deg - k;
    if (2 * s < r) {
        int4 p = rec4[(k >> 1) + s];
        h16x4 f0 = ld_h4(hb + (p.x << sh) + qb);
        fma4h(a2, __int_as_float(p.y), f0);
        if (2 * s + 1 < r) {
            h16x4 f1 = ld_h4(hb + (p.z << sh) + qb);
            fma4h(a3, __int_as_float(p.w), f1);
        }
    }
    a0.x += a1.x; a0.y += a1.y; a0.z += a1.z; a0.w += a1.w;
    a2.x += a3.x; a2.y += a3.y; a2.z += a3.z; a2.w += a3.w;
    a0.x += a2.x; a0.y += a2.y; a0.z += a2.z; a0.w += a2.w;
    return red_s(a0);
}

// no LDS, no barrier: one wave per (node, dir); dirs write disjoint halves.
__global__ __launch_bounds__(256) void agg_kernel(
        const char* __restrict__ h_in, char* __restrict__ acc_out, int sh,
        const int* __restrict__ rowptrP, const int* __restrict__ deg_out,
        const int2* __restrict__ recA,
        const int* __restrict__ colptrP, const int* __restrict__ deg_in,
        const int2* __restrict__ recT) {
    const int tid  = threadIdx.x;
    const int wid  = (blockIdx.x << 2) + (tid >> 6);   // global wave id
    const int lane = tid & 63;
    const int node = wid >> 1;
    const int dir  = wid & 1;
    const int q = lane & 15;
    const int s = lane >> 4;

    const int* ptr = dir ? colptrP : rowptrP;
    const int* deg = dir ? deg_in : deg_out;
    const int2* rec = dir ? recT : recA;

    float4 a = agg_dir(h_in, rec, ptr[node], deg[node], q, s, sh);
    if (s == 0) {
        h16x4 pk;
        pk.x = (h16)a.x; pk.y = (h16)a.y; pk.z = (h16)a.z; pk.w = (h16)a.w;
        *(h16x4*)(acc_out + (size_t)node * 256 + dir * 128 + q * 8) = pk;
    }
}

// --------------------------------------- GEMM via MFMA, h written in place
// acc rows are 256B ([128] fp16); h = ReLU(acc @ WT^T + bc) written into the
// first 128B of each row. Optional fused max-pool (layer 3): batch is sorted,
// so most 16-node tiles map to one graph -> shfl-reduce + 1 atomic per feat.
__global__ __launch_bounds__(256) void gemm_kernel(char* __restrict__ acc,
                                                   const h16* __restrict__ WT,
                                                   const float* __restrict__ bc,
                                                   const int* __restrict__ batch,
                                                   unsigned* __restrict__ g,
                                                   int do_pool) {
    const int lane = threadIdx.x & 63;
    const int wid = (blockIdx.x * 256 + threadIdx.x) >> 6;
    const int nW = gridDim.x * 4;
    const int m = lane & 15, t = lane >> 4;

    h16x8 bfrag[4][4];
    float bb[4];
#pragma unroll
    for (int nt = 0; nt < 4; nt++) {
        bb[nt] = bc[nt * 16 + m];
#pragma unroll
        for (int kk = 0; kk < 4; kk++)
            bfrag[nt][kk] = *(const h16x8*)(WT + (nt * 16 + m) * 128 + kk * 32 + t * 8);
    }

    for (int tile = wid; tile < MTILES; tile += nW) {
        char* arow = acc + (size_t)tile * 16 * 256;
        const int node0 = tile * 16;
        int b0 = 0, b15 = 0;
        if (do_pool) { b0 = batch[node0]; b15 = batch[node0 + 15]; }
        h16x8 afrag[4];
#pragma unroll
        for (int kk = 0; kk < 4; kk++)
            afrag[kk] = *(const h16x8*)(arow + m * 256 + kk * 64 + t * 16);
#pragma unroll
        for (int nt = 0; nt < 4; nt++) {
            f32x4 c = {0.f, 0.f, 0.f, 0.f};
#pragma unroll
            for (int kk = 0; kk < 4; kk++)
                c = __builtin_amdgcn_mfma_f32_16x16x32_f16(afrag[kk], bfrag[nt][kk], c, 0, 0, 0);
            float ov[4];
#pragma unroll
            for (int r = 0; r < 4; r++) {
                ov[r] = fmaxf(c[r] + bb[nt], 0.0f);
                *(h16*)(arow + (t * 4 + r) * 256 + (nt * 16 + m) * 2) = (h16)ov[r];
            }
            if (do_pool) {
                if (b0 == b15) {
                    float mx = fmaxf(fmaxf(ov[0], ov[1]), fmaxf(ov[2], ov[3]));
                    mx = fmaxf(mx, __shfl_xor(mx, 16));
                    mx = fmaxf(mx, __shfl_xor(mx, 32));
                    if (t == 0)
                        atomicMax(&g[b0 * HDIM + nt * 16 + m], __float_as_uint(mx));
                } else {
#pragma unroll
                    for (int r = 0; r < 4; r++)
                        atomicMax(&g[batch[node0 + t * 4 + r] * HDIM + nt * 16 + m],
                                  __float_as_uint(ov[r]));
                }
            }
        }
    }
}

// -------------------------------------------------------------------- MLP head
__global__ __launch_bounds__(64) void mlp_kernel(const unsigned* __restrict__ g,
                                                 const float* __restrict__ wl1,
                                                 const float* __restrict__ bl1,
                                                 const float* __restrict__ wl2,
                                                 const float* __restrict__ bl2,
                                                 float* __restrict__ out) {
    int t = threadIdx.x;   // graph index, one block of 64
    float gv[HDIM];
#pragma unroll
    for (int k = 0; k < HDIM; k++) gv[k] = __uint_as_float(g[t * HDIM + k]);
    float o = bl2[0];
#pragma unroll
    for (int j = 0; j < 5; j++) {
        float hj = bl1[j];
#pragma unroll
        for (int k = 0; k < HDIM; k++) hj += gv[k] * wl1[k * 5 + j];
        hj = fmaxf(hj, 0.0f);
        o += hj * wl2[j];
    }
    out[t] = o;
}

// ------------------------------------------------------------------- launch
extern "C" void kernel_launch(void* const* d_in, const int* in_sizes, int n_in,
                              void* d_out, int out_size, void* d_ws, size_t ws_size,
                              hipStream_t stream) {
    const float* x   = (const float*)d_in[0];
    const int*   ei  = (const int*)d_in[1];
    const int*   bat = (const int*)d_in[2];
    const float* w1s = (const float*)d_in[3];
    const float* b1s = (const float*)d_in[4];
    const float* w1d = (const float*)d_in[5];
    const float* b1d = (const float*)d_in[6];
    const float* w2s = (const float*)d_in[7];
    const float* b2s = (const float*)d_in[8];
    const float* w2d = (const float*)d_in[9];
    const float* b2d = (const float*)d_in[10];
    const float* w3s = (const float*)d_in[11];
    const float* b3s = (const float*)d_in[12];
    const float* w3d = (const float*)d_in[13];
    const float* b3d = (const float*)d_in[14];
    const float* wl1 = (const float*)d_in[15];
    const float* bl1 = (const float*)d_in[16];
    const float* wl2 = (const float*)d_in[17];
    const float* bl2 = (const float*)d_in[18];
    float* out = (float*)d_out;

    // Workspace. bufP (25.6MB) = bkt region (bkt dead before layer1 agg).
    // bufQ (25.6MB): first half doubles as xh (dead before layer2 agg writes).
    char* p = (char*)d_ws;
    int*   deg_out = (int*)p;              p += N_NODES * 4;
    int*   deg_in  = (int*)p;              p += N_NODES * 4;
    int*   rowptrP = (int*)p;              p += N_NODES * 4;
    int*   colptrP = (int*)p;              p += N_NODES * 4;
    float* r_out   = (float*)p;            p += N_NODES * 4;
    float* r_in    = (float*)p;            p += N_NODES * 4;
    int*   cntTabA = (int*)p;              p += (size_t)NB * NBLK * 4;
    int*   cntTabT = (int*)p;              p += (size_t)NB * NBLK * 4;
    int*   totTab  = (int*)p;              p += 1024 * 4;
    int*   bktStartA = (int*)p;            p += 512 * 4;
    int*   bktStartT = (int*)p;            p += 512 * 4;
    int2*  recA    = (int2*)p;             p += (size_t)EPAD * 8;
    int2*  recT    = (int2*)p;             p += (size_t)EPAD * 8;
    char*  bufP    = p;                    // 25.6MB: bktA | bktT during prep
    int2*  bktA    = (int2*)p;
    int2*  bktT    = (int2*)(p + (size_t)N_EDGES * 8);
    p += 2 * (size_t)N_EDGES * 8;
    char*  bufQ    = p;                    // 25.6MB: xh in first half
    h16*   xh      = (h16*)p;
    p += 2 * (size_t)N_EDGES * 8;
    unsigned* g    = (unsigned*)p;         p += NGRAPH * HDIM * 4;
    h16*   WT      = (h16*)p;              p += 3 * 8192 * 2;
    float* bc      = (float*)p;            p += 3 * 64 * 4;

    cast_kernel<<<(N_NODES * 16 + 255) / 256, 256, 0, stream>>>(
        (const float4*)x, (h16x4*)xh, g);
    dim3 gw(32, 3);
    wprep_kernel<<<gw, 256, 0, stream>>>(w1s, w1d, w2s, w2d, w3s, w3d,
                                         b1s, b1d, b2s, b2d, b3s, b3d, WT, bc);

    bucket_count<<<NBLK, 512, 0, stream>>>(ei, cntTabA, cntTabT);
    dim3 gb2(NB, 2);
    chunk_scan<<<gb2, 256, 0, stream>>>(cntTabA, cntTabT, totTab);
    start_scan<<<1, 512, 0, stream>>>(totTab, bktStartA, bktStartT);
    bucketize_write<<<NBLK, 512, 0, stream>>>(ei, cntTabA, cntTabT,
                                              bktStartA, bktStartT, bktA, bktT);

    dim3 gb(NB, 2);
    bucket_deg_ptr<<<gb, 256, 0, stream>>>(bktStartA, bktStartT, bktA, bktT,
                                           deg_out, deg_in, r_out, r_in,
                                           rowptrP, colptrP);
    bucket_scatter<<<gb, 512, 0, stream>>>(
        rowptrP, colptrP, r_out, r_in, bktStartA, bktStartT, bktA, bktT, recA, recT);

    const int agrid = N_NODES * 2 / 4;    // one wave per (node,dir), 4 waves/block
    // Layer 1: xh (128B rows) -> bufP
    agg_kernel<<<agrid, 256, 0, stream>>>((const char*)xh, bufP, 0,
                                          rowptrP, deg_out, recA, colptrP, deg_in, recT);
    gemm_kernel<<<256, 256, 0, stream>>>(bufP, WT, bc, bat, g, 0);
    // Layer 2: bufP (256B rows) -> bufQ
    agg_kernel<<<agrid, 256, 0, stream>>>(bufP, bufQ, 1,
                                          rowptrP, deg_out, recA, colptrP, deg_in, recT);
    gemm_kernel<<<256, 256, 0, stream>>>(bufQ, WT + 8192, bc + 64, bat, g, 0);
    // Layer 3: bufQ -> bufP, fused max-pool
    agg_kernel<<<agrid, 256, 0, stream>>>(bufQ, bufP, 1,
                                          rowptrP, deg_out, recA, colptrP, deg_in, recT);
    gemm_kernel<<<256, 256, 0, stream>>>(bufP, WT + 16384, bc + 128, bat, g, 1);

    mlp_kernel<<<1, 64, 0, stream>>>(g, wl1, bl1, wl2, bl2, out);
}